// Round 5
// baseline (70.716 us; speedup 1.0000x reference)
//
#include <hip/hip_runtime.h>
#include <math.h>

#define EPSF 1e-6f
#define N_PTS 1024
#define BT 32
#define RC 16          // ref chunks per (batch, dir); chunk = 64 points
#define CHUNK 64
#define NPAIR (CHUNK / 2)

typedef float v2f __attribute__((ext_vector_type(2)));
typedef float v4f __attribute__((ext_vector_type(4)));

// ---------------------------------------------------------------------------
// Stage: grid (16 ref-chunks, 32 batches, 2 directions) x 128 threads.
// Q=8 queries/thread. Ref chunk staged in LDS in PAIR-SoA layout:
//   sa[p] = (-2rx_e, -2rx_o, -2ry_e, -2ry_o)
//   sb[p] = (-2rz_e, -2rz_o,  r2_e,   r2_o)
// so one ref PAIR costs 2 broadcast ds_read_b128 and, per query,
//   3 x v_pk_fma_f32 (both refs' 3-FMA chains in packed halves)
// + 1 x v_min3_f32   (m = min(m, v.lo, v.hi))
// = 4 VALU inst / 2 refs / query (was 7 scalar). Query coords are
// pre-splatted into both halves. q2 hoisted out of the min.
// 1024 blocks -> 4 blocks/CU, 2 waves/SIMD.
// Writes min-sq partials to ws[(dirb*RC+rc)*1024 + q] (coalesced).
// ---------------------------------------------------------------------------
__global__ __launch_bounds__(128) void chamfer_stage(
    const float* __restrict__ x, const float* __restrict__ y,
    float* __restrict__ ws) {
  const int t   = threadIdx.x;
  const int rc  = blockIdx.x;   // 0..15
  const int b   = blockIdx.y;   // 0..31
  const int dir = blockIdx.z;   // 0: query=x ref=y ; 1: swapped

  const float* qarr = dir ? y : x;
  const float* rarr = dir ? x : y;
  const float* qb = qarr + (size_t)b * (N_PTS * 3);
  const float* rb = rarr + (size_t)b * (N_PTS * 3) + (size_t)rc * (CHUNK * 3);

  __shared__ v4f sa[NPAIR];
  __shared__ v4f sb[NPAIR];
  if (t < NPAIR) {
    const float xe = rb[t * 6 + 0], ye = rb[t * 6 + 1], ze = rb[t * 6 + 2];
    const float xo = rb[t * 6 + 3], yo = rb[t * 6 + 4], zo = rb[t * 6 + 5];
    v4f a, bb;
    a.x = -2.0f * xe; a.y = -2.0f * xo; a.z = -2.0f * ye; a.w = -2.0f * yo;
    bb.x = -2.0f * ze; bb.y = -2.0f * zo;
    bb.z = xe * xe + ye * ye + ze * ze;
    bb.w = xo * xo + yo * yo + zo * zo;
    sa[t] = a; sb[t] = bb;
  }
  __syncthreads();

  v2f qx2[8], qy2[8], qz2[8];
  float q2[8], m[8];
#pragma unroll
  for (int k = 0; k < 8; ++k) {
    const int j = t + 128 * k;
    const float qx = qb[j * 3 + 0];
    const float qy = qb[j * 3 + 1];
    const float qz = qb[j * 3 + 2];
    qx2[k].x = qx; qx2[k].y = qx;
    qy2[k].x = qy; qy2[k].y = qy;
    qz2[k].x = qz; qz2[k].y = qz;
    q2[k] = qx * qx + qy * qy + qz * qz;
    m[k] = 3.4e38f;
  }

#pragma unroll 4
  for (int p = 0; p < NPAIR; ++p) {
    const v4f a = sa[p];
    const v4f bb = sb[p];
    const v2f rx2 = a.xy;
    const v2f ry2 = a.zw;
    const v2f rz2 = bb.xy;
    const v2f rw2 = bb.zw;
#pragma unroll
    for (int k = 0; k < 8; ++k) {
      v2f v;
      asm("v_pk_fma_f32 %0, %1, %2, %3"
          : "=v"(v) : "v"(qx2[k]), "v"(rx2), "v"(rw2));
      asm("v_pk_fma_f32 %0, %1, %2, %0"
          : "+v"(v) : "v"(qy2[k]), "v"(ry2));
      asm("v_pk_fma_f32 %0, %1, %2, %0"
          : "+v"(v) : "v"(qz2[k]), "v"(rz2));
      m[k] = fminf(m[k], fminf(v.x, v.y));  // -> v_min3_f32
    }
  }

  float* wbase = ws + ((size_t)(dir * BT + b) * RC + rc) * N_PTS;
#pragma unroll
  for (int k = 0; k < 8; ++k) {
    const int j = t + 128 * k;
    wbase[j] = fmaxf(q2[k] + m[k], 0.0f);  // clamp commutes with min
  }
}

// ---------------------------------------------------------------------------
// Reduce: 65536 (dirb, query) entries, 2 queries/thread via float2 loads.
// 128 blocks x 256 threads; 16 coalesced 8B loads/thread (stride 512 float2
// over rc), componentwise min, sqrt(eps+.), wave+block sum, 1 atomic/block.
// ---------------------------------------------------------------------------
__global__ __launch_bounds__(256) void chamfer_reduce(
    const float* __restrict__ ws, float* __restrict__ out) {
  const int g = blockIdx.x * 256 + threadIdx.x;   // 0..32767 (query pairs)
  const int dirb = g >> 9;
  const int qp = g & 511;
  const float2* p = (const float2*)ws + (size_t)dirb * RC * 512 + qp;
  float2 mn = p[0];
#pragma unroll
  for (int r = 1; r < RC; ++r) {
    const float2 v = p[(size_t)r * 512];
    mn.x = fminf(mn.x, v.x);
    mn.y = fminf(mn.y, v.y);
  }
  float d = sqrtf(EPSF + mn.x) + sqrtf(EPSF + mn.y);

  for (int off = 32; off > 0; off >>= 1) d += __shfl_down(d, off, 64);

  __shared__ float wsum[4];
  if ((threadIdx.x & 63) == 0) wsum[threadIdx.x >> 6] = d;
  __syncthreads();
  if (threadIdx.x == 0) {
    atomicAdd(out, (wsum[0] + wsum[1] + wsum[2] + wsum[3]) * (1.0f / 32768.0f));
  }
}

// ---------------------------------------------------------------------------
// Fallback (no workspace): full-ref LDS tile, 1 query/thread, atomicAdd.
// ---------------------------------------------------------------------------
__global__ __launch_bounds__(256) void chamfer_simple(
    const float* __restrict__ x, const float* __restrict__ y,
    float* __restrict__ out) {
  const int t   = threadIdx.x;
  const int qc  = blockIdx.x;
  const int b   = blockIdx.y;
  const int dir = blockIdx.z;

  const float* qarr = dir ? y : x;
  const float* rarr = dir ? x : y;
  const float* qb = qarr + (size_t)b * N_PTS * 3;
  const float* rb = rarr + (size_t)b * N_PTS * 3;

  __shared__ float4 s[N_PTS];
  for (int i = t; i < N_PTS; i += 256) {
    const float rx = rb[i * 3], ry = rb[i * 3 + 1], rz = rb[i * 3 + 2];
    s[i] = make_float4(-2.0f * rx, -2.0f * ry, -2.0f * rz,
                       rx * rx + ry * ry + rz * rz);
  }
  __syncthreads();

  const int j = qc * 256 + t;
  const float qx = qb[j * 3], qy = qb[j * 3 + 1], qz = qb[j * 3 + 2];
  const float q2 = qx * qx + qy * qy + qz * qz;
  float m = 3.4e38f;
#pragma unroll 8
  for (int i = 0; i < N_PTS; i += 2) {
    const float4 r0 = s[i];
    const float4 r1 = s[i + 1];
    float v0 = fmaf(qx, r0.x, r0.w);
    v0 = fmaf(qy, r0.y, v0);
    v0 = fmaf(qz, r0.z, v0);
    float v1 = fmaf(qx, r1.x, r1.w);
    v1 = fmaf(qy, r1.y, v1);
    v1 = fmaf(qz, r1.z, v1);
    m = fminf(m, fminf(v0, v1));
  }
  float d = sqrtf(EPSF + fmaxf(q2 + m, 0.0f));

  for (int off = 32; off > 0; off >>= 1) d += __shfl_down(d, off, 64);

  __shared__ float wsum[4];
  if ((t & 63) == 0) wsum[t >> 6] = d;
  __syncthreads();
  if (t == 0) {
    atomicAdd(out, (wsum[0] + wsum[1] + wsum[2] + wsum[3]) * (1.0f / 32768.0f));
  }
}

extern "C" void kernel_launch(void* const* d_in, const int* in_sizes, int n_in,
                              void* d_out, int out_size, void* d_ws, size_t ws_size,
                              hipStream_t stream) {
  const float* x = (const float*)d_in[0];
  const float* y = (const float*)d_in[1];
  float* out = (float*)d_out;

  // d_out is re-poisoned to 0xAA before every timed replay; zero it first.
  hipMemsetAsync(out, 0, sizeof(float) * out_size, stream);

  const size_t ws_need = (size_t)2 * BT * RC * N_PTS * sizeof(float);  // 4 MiB
  if (ws_size >= ws_need) {
    chamfer_stage<<<dim3(RC, BT, 2), 128, 0, stream>>>(x, y, (float*)d_ws);
    chamfer_reduce<<<dim3(128), 256, 0, stream>>>((const float*)d_ws, out);
  } else {
    chamfer_simple<<<dim3(4, BT, 2), 256, 0, stream>>>(x, y, out);
  }
}

// Round 6
// 68.557 us; speedup vs baseline: 1.0315x; 1.0315x over previous
//
#include <hip/hip_runtime.h>
#include <math.h>

#define EPSF 1e-6f
#define N_PTS 1024
#define BT 32
#define RC 16          // ref chunks per (batch, dir); chunk = 64 points
#define CHUNK 64

// ---------------------------------------------------------------------------
// Stage: grid (16 ref-chunks, 32 batches, 2 directions) x 128 threads.
// Q=8 queries/thread (block covers all 1024 queries of its batch).
// Ref chunk (64 pts) staged in LDS as float4(-2rx,-2ry,-2rz,r2); one
// broadcast ds_read_b128 per ref serves 8 queries. Refs processed in PAIRS:
//   v0 = 3-FMA chain(ref i), v1 = 3-FMA chain(ref i+1),
//   m  = fminf(m, fminf(v0, v1))        -> single v_min3_f32
// = 7 VALU inst per 2 refs per query. q2 hoisted out of the min.
// Query loads are issued BEFORE the staging barrier (independent of LDS) so
// their global latency overlaps the ref-stage wait at 2 waves/SIMD.
// NOTE (R5 post-mortem): v_pk_fma_f32 via inline asm REGRESSED (+3.7us) —
// asm blocks scheduling and adds sub-vector movs; scalar FMA+min3 is best.
// 1024 blocks -> 4 blocks/CU, 2 waves/SIMD; LDS pipe ~2.6us hidden.
// Writes min-sq partials to ws[(dirb*RC+rc)*1024 + q] (coalesced).
// ---------------------------------------------------------------------------
__global__ __launch_bounds__(128) void chamfer_stage(
    const float* __restrict__ x, const float* __restrict__ y,
    float* __restrict__ ws) {
  const int t   = threadIdx.x;
  const int rc  = blockIdx.x;   // 0..15
  const int b   = blockIdx.y;   // 0..31
  const int dir = blockIdx.z;   // 0: query=x ref=y ; 1: swapped

  const float* qarr = dir ? y : x;
  const float* rarr = dir ? x : y;
  const float* qb = qarr + (size_t)b * (N_PTS * 3);
  const float* rb = rarr + (size_t)b * (N_PTS * 3) + (size_t)rc * (CHUNK * 3);

  __shared__ float4 s[CHUNK];

  // Issue query loads first — independent of LDS, overlaps staging latency.
  float qx[8], qy[8], qz[8], q2[8], m[8];
#pragma unroll
  for (int k = 0; k < 8; ++k) {
    const int j = t + 128 * k;
    qx[k] = qb[j * 3 + 0];
    qy[k] = qb[j * 3 + 1];
    qz[k] = qb[j * 3 + 2];
  }

  if (t < CHUNK) {
    const float rx = rb[t * 3 + 0];
    const float ry = rb[t * 3 + 1];
    const float rz = rb[t * 3 + 2];
    s[t] = make_float4(-2.0f * rx, -2.0f * ry, -2.0f * rz,
                       rx * rx + ry * ry + rz * rz);
  }

#pragma unroll
  for (int k = 0; k < 8; ++k) {
    q2[k] = qx[k] * qx[k] + qy[k] * qy[k] + qz[k] * qz[k];
    m[k] = 3.4e38f;
  }
  __syncthreads();

#pragma unroll 4
  for (int i = 0; i < CHUNK; i += 2) {
    const float4 r0 = s[i];
    const float4 r1 = s[i + 1];
#pragma unroll
    for (int k = 0; k < 8; ++k) {
      float v0 = fmaf(qx[k], r0.x, r0.w);
      v0 = fmaf(qy[k], r0.y, v0);
      v0 = fmaf(qz[k], r0.z, v0);
      float v1 = fmaf(qx[k], r1.x, r1.w);
      v1 = fmaf(qy[k], r1.y, v1);
      v1 = fmaf(qz[k], r1.z, v1);
      m[k] = fminf(m[k], fminf(v0, v1));  // -> v_min3_f32
    }
  }

  float* wbase = ws + ((size_t)(dir * BT + b) * RC + rc) * N_PTS;
#pragma unroll
  for (int k = 0; k < 8; ++k) {
    const int j = t + 128 * k;
    wbase[j] = fmaxf(q2[k] + m[k], 0.0f);  // clamp commutes with min
  }
}

// ---------------------------------------------------------------------------
// Reduce: 65536 (dirb, query) entries, 2 queries/thread via float2 loads.
// 128 blocks x 256 threads; 16 coalesced 8B loads/thread (stride 512 float2
// over rc), componentwise min, sqrt(eps+.), wave+block sum, 1 atomic/block.
// ---------------------------------------------------------------------------
__global__ __launch_bounds__(256) void chamfer_reduce(
    const float* __restrict__ ws, float* __restrict__ out) {
  const int g = blockIdx.x * 256 + threadIdx.x;   // 0..32767 (query pairs)
  const int dirb = g >> 9;
  const int qp = g & 511;
  const float2* p = (const float2*)ws + (size_t)dirb * RC * 512 + qp;
  float2 mn = p[0];
#pragma unroll
  for (int r = 1; r < RC; ++r) {
    const float2 v = p[(size_t)r * 512];
    mn.x = fminf(mn.x, v.x);
    mn.y = fminf(mn.y, v.y);
  }
  float d = sqrtf(EPSF + mn.x) + sqrtf(EPSF + mn.y);

  for (int off = 32; off > 0; off >>= 1) d += __shfl_down(d, off, 64);

  __shared__ float wsum[4];
  if ((threadIdx.x & 63) == 0) wsum[threadIdx.x >> 6] = d;
  __syncthreads();
  if (threadIdx.x == 0) {
    atomicAdd(out, (wsum[0] + wsum[1] + wsum[2] + wsum[3]) * (1.0f / 32768.0f));
  }
}

// ---------------------------------------------------------------------------
// Fallback (no workspace): full-ref LDS tile, 1 query/thread, atomicAdd.
// ---------------------------------------------------------------------------
__global__ __launch_bounds__(256) void chamfer_simple(
    const float* __restrict__ x, const float* __restrict__ y,
    float* __restrict__ out) {
  const int t   = threadIdx.x;
  const int qc  = blockIdx.x;
  const int b   = blockIdx.y;
  const int dir = blockIdx.z;

  const float* qarr = dir ? y : x;
  const float* rarr = dir ? x : y;
  const float* qb = qarr + (size_t)b * N_PTS * 3;
  const float* rb = rarr + (size_t)b * N_PTS * 3;

  __shared__ float4 s[N_PTS];
  for (int i = t; i < N_PTS; i += 256) {
    const float rx = rb[i * 3], ry = rb[i * 3 + 1], rz = rb[i * 3 + 2];
    s[i] = make_float4(-2.0f * rx, -2.0f * ry, -2.0f * rz,
                       rx * rx + ry * ry + rz * rz);
  }
  __syncthreads();

  const int j = qc * 256 + t;
  const float qx = qb[j * 3], qy = qb[j * 3 + 1], qz = qb[j * 3 + 2];
  const float q2 = qx * qx + qy * qy + qz * qz;
  float m = 3.4e38f;
#pragma unroll 8
  for (int i = 0; i < N_PTS; i += 2) {
    const float4 r0 = s[i];
    const float4 r1 = s[i + 1];
    float v0 = fmaf(qx, r0.x, r0.w);
    v0 = fmaf(qy, r0.y, v0);
    v0 = fmaf(qz, r0.z, v0);
    float v1 = fmaf(qx, r1.x, r1.w);
    v1 = fmaf(qy, r1.y, v1);
    v1 = fmaf(qz, r1.z, v1);
    m = fminf(m, fminf(v0, v1));
  }
  float d = sqrtf(EPSF + fmaxf(q2 + m, 0.0f));

  for (int off = 32; off > 0; off >>= 1) d += __shfl_down(d, off, 64);

  __shared__ float wsum[4];
  if ((t & 63) == 0) wsum[t >> 6] = d;
  __syncthreads();
  if (t == 0) {
    atomicAdd(out, (wsum[0] + wsum[1] + wsum[2] + wsum[3]) * (1.0f / 32768.0f));
  }
}

extern "C" void kernel_launch(void* const* d_in, const int* in_sizes, int n_in,
                              void* d_out, int out_size, void* d_ws, size_t ws_size,
                              hipStream_t stream) {
  const float* x = (const float*)d_in[0];
  const float* y = (const float*)d_in[1];
  float* out = (float*)d_out;

  // d_out is re-poisoned to 0xAA before every timed replay; zero it first.
  hipMemsetAsync(out, 0, sizeof(float) * out_size, stream);

  const size_t ws_need = (size_t)2 * BT * RC * N_PTS * sizeof(float);  // 4 MiB
  if (ws_size >= ws_need) {
    chamfer_stage<<<dim3(RC, BT, 2), 128, 0, stream>>>(x, y, (float*)d_ws);
    chamfer_reduce<<<dim3(128), 256, 0, stream>>>((const float*)d_ws, out);
  } else {
    chamfer_simple<<<dim3(4, BT, 2), 256, 0, stream>>>(x, y, out);
  }
}

// Round 7
// 67.276 us; speedup vs baseline: 1.0511x; 1.0190x over previous
//
#include <hip/hip_runtime.h>
#include <math.h>

#define EPSF 1e-6f
#define N_PTS 1024
#define BT 32
#define RC 16          // ref chunks per (batch, dir); chunk = 64 points
#define CHUNK 64

// ---------------------------------------------------------------------------
// Stage: grid (16 ref-chunks, 32 batches, 2 directions) x 128 threads.
// Q=8 queries/thread (block covers all 1024 queries of its batch).
// Ref chunk (64 pts) staged in LDS as float4(-2rx,-2ry,-2rz,r2); one
// broadcast ds_read_b128 per ref serves 8 queries. Refs processed in PAIRS:
//   v0 = 3-FMA chain(ref i), v1 = 3-FMA chain(ref i+1),
//   m  = fminf(m, fminf(v0, v1))        -> single v_min3_f32
// = 7 VALU inst per 2 refs per query. q2 hoisted out of the min.
// NOTE (R5): v_pk_fma_f32 via inline asm REGRESSED (+3.7us) — asm blocks
// scheduling and adds sub-vector movs; scalar FMA+min3 is the issue floor.
// NOTE (R6): hoisting query loads above the staging barrier REGRESSED
// (+1.6us) — lengthens the pre-barrier critical path; keep them here.
// 1024 blocks -> 4 blocks/CU, 2 waves/SIMD; LDS pipe ~2.6us hidden.
// Writes min-sq partials to ws[(dirb*RC+rc)*1024 + q] (coalesced).
// ---------------------------------------------------------------------------
__global__ __launch_bounds__(128) void chamfer_stage(
    const float* __restrict__ x, const float* __restrict__ y,
    float* __restrict__ ws) {
  const int t   = threadIdx.x;
  const int rc  = blockIdx.x;   // 0..15
  const int b   = blockIdx.y;   // 0..31
  const int dir = blockIdx.z;   // 0: query=x ref=y ; 1: swapped

  const float* qarr = dir ? y : x;
  const float* rarr = dir ? x : y;
  const float* qb = qarr + (size_t)b * (N_PTS * 3);
  const float* rb = rarr + (size_t)b * (N_PTS * 3) + (size_t)rc * (CHUNK * 3);

  __shared__ float4 s[CHUNK];
  if (t < CHUNK) {
    const float rx = rb[t * 3 + 0];
    const float ry = rb[t * 3 + 1];
    const float rz = rb[t * 3 + 2];
    s[t] = make_float4(-2.0f * rx, -2.0f * ry, -2.0f * rz,
                       rx * rx + ry * ry + rz * rz);
  }
  __syncthreads();

  float qx[8], qy[8], qz[8], q2[8], m[8];
#pragma unroll
  for (int k = 0; k < 8; ++k) {
    const int j = t + 128 * k;
    qx[k] = qb[j * 3 + 0];
    qy[k] = qb[j * 3 + 1];
    qz[k] = qb[j * 3 + 2];
    q2[k] = qx[k] * qx[k] + qy[k] * qy[k] + qz[k] * qz[k];
    m[k] = 3.4e38f;
  }

#pragma unroll 4
  for (int i = 0; i < CHUNK; i += 2) {
    const float4 r0 = s[i];
    const float4 r1 = s[i + 1];
#pragma unroll
    for (int k = 0; k < 8; ++k) {
      float v0 = fmaf(qx[k], r0.x, r0.w);
      v0 = fmaf(qy[k], r0.y, v0);
      v0 = fmaf(qz[k], r0.z, v0);
      float v1 = fmaf(qx[k], r1.x, r1.w);
      v1 = fmaf(qy[k], r1.y, v1);
      v1 = fmaf(qz[k], r1.z, v1);
      m[k] = fminf(m[k], fminf(v0, v1));  // -> v_min3_f32
    }
  }

  float* wbase = ws + ((size_t)(dir * BT + b) * RC + rc) * N_PTS;
#pragma unroll
  for (int k = 0; k < 8; ++k) {
    const int j = t + 128 * k;
    wbase[j] = fmaxf(q2[k] + m[k], 0.0f);  // clamp commutes with min
  }
}

// ---------------------------------------------------------------------------
// Reduce: 65536 (dirb, query) entries, 2 queries/thread via float2 loads.
// 128 blocks x 256 threads; 16 coalesced 8B loads/thread (stride 512 float2
// over rc), componentwise min, sqrt(eps+.), wave+block sum, 1 atomic/block.
// ---------------------------------------------------------------------------
__global__ __launch_bounds__(256) void chamfer_reduce(
    const float* __restrict__ ws, float* __restrict__ out) {
  const int g = blockIdx.x * 256 + threadIdx.x;   // 0..32767 (query pairs)
  const int dirb = g >> 9;
  const int qp = g & 511;
  const float2* p = (const float2*)ws + (size_t)dirb * RC * 512 + qp;
  float2 mn = p[0];
#pragma unroll
  for (int r = 1; r < RC; ++r) {
    const float2 v = p[(size_t)r * 512];
    mn.x = fminf(mn.x, v.x);
    mn.y = fminf(mn.y, v.y);
  }
  float d = sqrtf(EPSF + mn.x) + sqrtf(EPSF + mn.y);

  for (int off = 32; off > 0; off >>= 1) d += __shfl_down(d, off, 64);

  __shared__ float wsum[4];
  if ((threadIdx.x & 63) == 0) wsum[threadIdx.x >> 6] = d;
  __syncthreads();
  if (threadIdx.x == 0) {
    atomicAdd(out, (wsum[0] + wsum[1] + wsum[2] + wsum[3]) * (1.0f / 32768.0f));
  }
}

// ---------------------------------------------------------------------------
// Fallback (no workspace): full-ref LDS tile, 1 query/thread, atomicAdd.
// ---------------------------------------------------------------------------
__global__ __launch_bounds__(256) void chamfer_simple(
    const float* __restrict__ x, const float* __restrict__ y,
    float* __restrict__ out) {
  const int t   = threadIdx.x;
  const int qc  = blockIdx.x;
  const int b   = blockIdx.y;
  const int dir = blockIdx.z;

  const float* qarr = dir ? y : x;
  const float* rarr = dir ? x : y;
  const float* qb = qarr + (size_t)b * N_PTS * 3;
  const float* rb = rarr + (size_t)b * N_PTS * 3;

  __shared__ float4 s[N_PTS];
  for (int i = t; i < N_PTS; i += 256) {
    const float rx = rb[i * 3], ry = rb[i * 3 + 1], rz = rb[i * 3 + 2];
    s[i] = make_float4(-2.0f * rx, -2.0f * ry, -2.0f * rz,
                       rx * rx + ry * ry + rz * rz);
  }
  __syncthreads();

  const int j = qc * 256 + t;
  const float qx = qb[j * 3], qy = qb[j * 3 + 1], qz = qb[j * 3 + 2];
  const float q2 = qx * qx + qy * qy + qz * qz;
  float m = 3.4e38f;
#pragma unroll 8
  for (int i = 0; i < N_PTS; i += 2) {
    const float4 r0 = s[i];
    const float4 r1 = s[i + 1];
    float v0 = fmaf(qx, r0.x, r0.w);
    v0 = fmaf(qy, r0.y, v0);
    v0 = fmaf(qz, r0.z, v0);
    float v1 = fmaf(qx, r1.x, r1.w);
    v1 = fmaf(qy, r1.y, v1);
    v1 = fmaf(qz, r1.z, v1);
    m = fminf(m, fminf(v0, v1));
  }
  float d = sqrtf(EPSF + fmaxf(q2 + m, 0.0f));

  for (int off = 32; off > 0; off >>= 1) d += __shfl_down(d, off, 64);

  __shared__ float wsum[4];
  if ((t & 63) == 0) wsum[t >> 6] = d;
  __syncthreads();
  if (t == 0) {
    atomicAdd(out, (wsum[0] + wsum[1] + wsum[2] + wsum[3]) * (1.0f / 32768.0f));
  }
}

extern "C" void kernel_launch(void* const* d_in, const int* in_sizes, int n_in,
                              void* d_out, int out_size, void* d_ws, size_t ws_size,
                              hipStream_t stream) {
  const float* x = (const float*)d_in[0];
  const float* y = (const float*)d_in[1];
  float* out = (float*)d_out;

  // d_out is re-poisoned to 0xAA before every timed replay; zero it first.
  hipMemsetAsync(out, 0, sizeof(float) * out_size, stream);

  const size_t ws_need = (size_t)2 * BT * RC * N_PTS * sizeof(float);  // 4 MiB
  if (ws_size >= ws_need) {
    chamfer_stage<<<dim3(RC, BT, 2), 128, 0, stream>>>(x, y, (float*)d_ws);
    chamfer_reduce<<<dim3(128), 256, 0, stream>>>((const float*)d_ws, out);
  } else {
    chamfer_simple<<<dim3(4, BT, 2), 256, 0, stream>>>(x, y, out);
  }
}